// Round 5
// baseline (857.157 us; speedup 1.0000x reference)
//
#include <hip/hip_runtime.h>
#include <stdint.h>

typedef unsigned short u16;
typedef __attribute__((ext_vector_type(8))) short bf16x8;
typedef __attribute__((ext_vector_type(4))) float f32x4;

__device__ __forceinline__ float bf2f(u16 u) {
  union { unsigned int i; float f; } v; v.i = ((unsigned int)u) << 16; return v.f;
}
__device__ __forceinline__ u16 f2bf(float f) {
  union { float f; unsigned int i; } v; v.f = f;
  unsigned int x = v.i;
  return (u16)((x + 0x7fffu + ((x >> 16) & 1u)) >> 16);  // RNE
}

__device__ __forceinline__ void async16(const void* g, void* l) {
  __builtin_amdgcn_global_load_lds(
      (const __attribute__((address_space(1))) void*)g,
      (__attribute__((address_space(3))) void*)l, 16, 0, 0);
}

// ---------------------------------------------------------------- casts ----
__global__ __launch_bounds__(256) void cast_f32_to_bf16(
    const float* __restrict__ x, u16* __restrict__ y, long n) {
  long i = ((long)blockIdx.x * blockDim.x + threadIdx.x) * 8;
  long stride = (long)gridDim.x * blockDim.x * 8;
  for (long j = i; j < n; j += stride) {
    float4 a = ((const float4*)(x + j))[0];
    float4 b = ((const float4*)(x + j))[1];
    unsigned int p0 = (unsigned)f2bf(a.x) | ((unsigned)f2bf(a.y) << 16);
    unsigned int p1 = (unsigned)f2bf(a.z) | ((unsigned)f2bf(a.w) << 16);
    unsigned int p2 = (unsigned)f2bf(b.x) | ((unsigned)f2bf(b.y) << 16);
    unsigned int p3 = (unsigned)f2bf(b.z) | ((unsigned)f2bf(b.w) << 16);
    *(uint4*)(y + j) = make_uint4(p0, p1, p2, p3);
  }
}

__global__ __launch_bounds__(256) void castWT(
    const float* __restrict__ Wq, const float* __restrict__ Wk,
    const float* __restrict__ Wv, const float* __restrict__ Wo,
    u16* __restrict__ WT) {
  int idx = blockIdx.x * 256 + threadIdx.x;  // n*512 + c
  int m = blockIdx.y;
  const float* src = (m == 0) ? Wq : (m == 1) ? Wk : (m == 2) ? Wv : Wo;
  int nn = idx >> 9;
  int cc = idx & 511;
  WT[(long)m * 262144 + idx] = f2bf(src[cc * 512 + nn]);
}

// --------------------------------------------------- 128x128 4-wave gemm ----
// m97 structure + swizzle + coalesced epilogue, tuned for TLP:
// 32 KiB LDS (2-buf ring), __launch_bounds__(256,4) -> 4 blocks/CU,
// 16 waves/CU. One __syncthreads per K-tile (implicit vmcnt(0) drain is
// hidden by the 3 other resident blocks). Stage-next is issued BEFORE the
// current tile's ds_read+MFMA (T3-minimum recipe).
// Read swizzle: byte ^= ((row>>1)&3)<<4 on 64 B rows (verified conflict-free);
// staging uses linear LDS dest + inverse-swizzled global source.
template <int MODE>
__global__ __launch_bounds__(256, 4) void gemm128(
    const u16* __restrict__ A, const u16* __restrict__ B,
    const float* __restrict__ bias, void* __restrict__ Cout,
    int N, int K, long sA, long sB, long sC, float scale) {
  __shared__ __align__(16) char lds[32768];  // buf*16384: A 8K | B 8K
  const int t = threadIdx.x;
  const int lane = t & 63;
  const int w = t >> 6;        // 0..3
  const int wm = w >> 1;       // 0..1
  const int wn = w & 1;        // 0..1
  const long z = blockIdx.z;
  const long m0 = (long)blockIdx.x * 128;
  const int n0 = blockIdx.y * 128;
  const int nt = K >> 5;       // BK=32 tiles

  // ---- staging geometry (linear LDS dest, inverse-swizzled global src) ----
  const int srow = w * 32 + (lane >> 2);                  // 0..127 (16/instr)
  const int koff = 8 * ((lane & 3) ^ ((lane >> 3) & 3));  // elems
  const u16* pa = A + z * sA + (m0 + srow) * (long)K + koff;
  const u16* pb = B + z * sB + ((long)(n0 + srow)) * K + koff;

  // ---- read geometry (swizzled ds_read_b128) ----
  const int fr = lane & 15;
  const int kb = (lane >> 4) * 16;                        // bytes
  const int sw = ((fr >> 1) & 3) << 4;
  const int aoff = (wm * 64 + fr) * 64 + (kb ^ sw);       // + mi*1024
  const int boff = 8192 + (wn * 64 + fr) * 64 + (kb ^ sw);  // + ni*1024

  f32x4 acc[4][4] = {};

  // ---- prologue: stage tile 0 into buf 0 ----
  {
    char* sA0 = lds + w * 2048;
    async16(pa, sA0);
    async16(pa + 16L * K, sA0 + 1024);
    char* sB0 = sA0 + 8192;
    async16(pb, sB0);
    async16(pb + 16L * K, sB0 + 1024);
    pa += 32;
    pb += 32;
  }
  __syncthreads();

  // ---- main loop: one barrier per tile ----
  int cur = 0;
  for (int tt = 0; tt < nt; ++tt) {
    if (tt + 1 < nt) {
      char* nA = lds + (cur ^ 1) * 16384 + w * 2048;
      async16(pa, nA);
      async16(pa + 16L * K, nA + 1024);
      char* nB = nA + 8192;
      async16(pb, nB);
      async16(pb + 16L * K, nB + 1024);
      pa += 32;
      pb += 32;
    }
    const char* rb = lds + cur * 16384;
    bf16x8 af[4], bf[4];
#pragma unroll
    for (int mi = 0; mi < 4; ++mi)
      af[mi] = *(const bf16x8*)(rb + aoff + mi * 1024);
#pragma unroll
    for (int ni = 0; ni < 4; ++ni)
      bf[ni] = *(const bf16x8*)(rb + boff + ni * 1024);
    __builtin_amdgcn_s_setprio(1);
#pragma unroll
    for (int mi = 0; mi < 4; ++mi)
#pragma unroll
      for (int ni = 0; ni < 4; ++ni)
        acc[mi][ni] = __builtin_amdgcn_mfma_f32_16x16x32_bf16(
            af[mi], bf[ni], acc[mi][ni], 0, 0, 0);
    __builtin_amdgcn_s_setprio(0);
    __syncthreads();
    cur ^= 1;
  }

  // ---- epilogue ----
  const int er = (lane >> 4) * 4;
  const int ec = lane & 15;
  if (MODE == 0) {
    // LDS-transposed coalesced store: 2 passes x 64 rows, stride 136 u16.
    u16* Ep = (u16*)lds;
    u16* Cp = (u16*)Cout + z * sC;
    float bv[4];
#pragma unroll
    for (int ni = 0; ni < 4; ++ni)
      bv[ni] = bias ? bias[n0 + wn * 64 + ni * 16 + ec] : 0.0f;
#pragma unroll
    for (int p = 0; p < 2; ++p) {
      __syncthreads();
      if (wm == p) {
#pragma unroll
        for (int mi = 0; mi < 4; ++mi) {
#pragma unroll
          for (int ni = 0; ni < 4; ++ni) {
#pragma unroll
            for (int i = 0; i < 4; ++i) {
              float val = acc[mi][ni][i] * scale + bv[ni];
              Ep[(mi * 16 + er + i) * 136 + wn * 64 + ni * 16 + ec] = f2bf(val);
            }
          }
        }
      }
      __syncthreads();
#pragma unroll
      for (int s = 0; s < 4; ++s) {
        int idx = s * 256 + t;
        int R = idx >> 4;       // 0..63
        int j = idx & 15;       // 0..15
        uint4 d = *(const uint4*)(Ep + R * 136 + j * 8);
        *(uint4*)(Cp + (m0 + p * 64 + R) * (long)N + n0 + j * 8) = d;
      }
    }
  } else {
#pragma unroll
    for (int mi = 0; mi < 4; ++mi) {
#pragma unroll
      for (int ni = 0; ni < 4; ++ni) {
#pragma unroll
        for (int i = 0; i < 4; ++i) {
          long gm = m0 + wm * 64 + mi * 16 + er + i;
          int gc = n0 + wn * 64 + ni * 16 + ec;
          float val = acc[mi][ni][i] * scale;
          if (bias) val += bias[gc];
          if (MODE == 1) {
            long b = gm >> 11, rr = gm & 2047;
            ((u16*)Cout)[b * ((long)N * 2048) + (long)gc * 2048 + rr] = f2bf(val);
          } else {
            ((float*)Cout + z * sC)[gm * (long)N + gc] = val;
          }
        }
      }
    }
  }
}

// ------------------------------------------------------------- softmax ----
__global__ __launch_bounds__(256) void softmax_rows(u16* __restrict__ S, float inv) {
  long row = blockIdx.x;
  u16* p = S + row * 2048;
  int t = threadIdx.x;
  int lane = t & 63, wv = t >> 6;

  uint4 raw = ((const uint4*)p)[t];
  unsigned int wd[4] = {raw.x, raw.y, raw.z, raw.w};
  float v[8];
#pragma unroll
  for (int j = 0; j < 4; ++j) {
    v[2 * j]     = bf2f((u16)(wd[j] & 0xffffu));
    v[2 * j + 1] = bf2f((u16)(wd[j] >> 16));
  }
  float mx = v[0];
#pragma unroll
  for (int j = 1; j < 8; ++j) mx = fmaxf(mx, v[j]);
  for (int off = 32; off; off >>= 1) mx = fmaxf(mx, __shfl_xor(mx, off));
  __shared__ float rmax[4], rsum[4];
  if (lane == 0) rmax[wv] = mx;
  __syncthreads();
  mx = fmaxf(fmaxf(rmax[0], rmax[1]), fmaxf(rmax[2], rmax[3]));

  float e[8], s = 0.f;
#pragma unroll
  for (int j = 0; j < 8; ++j) { e[j] = __expf(v[j] - mx); s += e[j]; }
  for (int off = 32; off; off >>= 1) s += __shfl_xor(s, off);
  if (lane == 0) rsum[wv] = s;
  __syncthreads();
  s = rsum[0] + rsum[1] + rsum[2] + rsum[3];

  float r = inv / s;
  unsigned int o[4];
#pragma unroll
  for (int j = 0; j < 4; ++j)
    o[j] = (unsigned)f2bf(e[2 * j] * r) | ((unsigned)f2bf(e[2 * j + 1] * r) << 16);
  ((uint4*)p)[t] = make_uint4(o[0], o[1], o[2], o[3]);
}

// -------------------------------------------------------------- launch ----
extern "C" void kernel_launch(void* const* d_in, const int* in_sizes, int n_in,
                              void* d_out, int out_size, void* d_ws, size_t ws_size,
                              hipStream_t stream) {
  const float* query = (const float*)d_in[0];
  const float* key_  = (const float*)d_in[1];
  const float* Wq = (const float*)d_in[2];
  const float* bq = (const float*)d_in[3];
  const float* Wk = (const float*)d_in[4];
  const float* bk = (const float*)d_in[5];
  const float* Wv = (const float*)d_in[6];
  const float* bv = (const float*)d_in[7];
  const float* Wo = (const float*)d_in[8];
  const float* bo = (const float*)d_in[9];
  float* out = (float*)d_out;

  const long tokE = 65536L * 512;
  const long bstride = 2048L * 512;

  char* ws = (char*)d_ws;
  u16* Qb = (u16*)(ws);
  u16* Kb = (u16*)(ws + 67108864L);
  u16* vT = (u16*)(ws + 134217728L);
  u16* WT = (u16*)(ws + 201326592L);
  char* Sbase = ws + 203423744L;
  u16* attn = Qb;  // Qb dead after q-projection

  u16* qb = (u16*)d_out;
  u16* kb = (u16*)((char*)d_out + 67108864L);

  long s_avail = (long)ws_size - 203423744L;
  int g = (int)(s_avail / 8388608L);
  if (g < 1) g = 1;
  if (g > 32) g = 32;

  // 1. casts
  cast_f32_to_bf16<<<16384, 256, 0, stream>>>(query, Qb, tokE);
  cast_f32_to_bf16<<<16384, 256, 0, stream>>>(key_, Kb, tokE);
  castWT<<<dim3(1024, 4, 1), 256, 0, stream>>>(Wq, Wk, Wv, Wo, WT);

  // 2. projections (M = 65536 merged)
  dim3 gproj(512, 4, 1);
  gemm128<0><<<gproj, 256, 0, stream>>>(Qb, WT,           bq, qb, 512, 512, 0, 0, 0, 1.0f);
  gemm128<0><<<gproj, 256, 0, stream>>>(Kb, WT + 262144L, bk, kb, 512, 512, 0, 0, 0, 1.0f);
  gemm128<1><<<gproj, 256, 0, stream>>>(Kb, WT + 524288L, bv, vT, 512, 512, 0, 0, 0, 1.0f);

  // 3. attention, grouped by available workspace
  for (int b0 = 0; b0 < 32; b0 += g) {
    int bc = (32 - b0 < g) ? (32 - b0) : g;
    u16* Sg = (u16*)Sbase;
    dim3 gs(16, 16, bc);
    gemm128<0><<<gs, 256, 0, stream>>>(qb + (long)b0 * bstride, kb + (long)b0 * bstride,
                                       nullptr, Sg, 2048, 512,
                                       bstride, bstride, 2048L * 2048, 1.0f / 512.0f);
    softmax_rows<<<bc * 2048, 256, 0, stream>>>(Sg, 1.0f / 2048.0f);
    dim3 gpv(16, 4, bc);
    gemm128<0><<<gpv, 256, 0, stream>>>(Sg, vT + (long)b0 * bstride, nullptr,
                                        attn + (long)b0 * bstride, 512, 2048,
                                        2048L * 2048, bstride, bstride, 1.0f);
  }

  // 4. output projection -> d_out fp32
  gemm128<2><<<dim3(512, 4, 1), 256, 0, stream>>>(attn, WT + 786432L, bo, out,
                                                  512, 512, 0, 0, 0, 1.0f);
}

// Round 6
// 769.168 us; speedup vs baseline: 1.1144x; 1.1144x over previous
//
#include <hip/hip_runtime.h>
#include <stdint.h>

typedef unsigned short u16;
typedef __attribute__((ext_vector_type(8))) short bf16x8;
typedef __attribute__((ext_vector_type(4))) float f32x4;

__device__ __forceinline__ float bf2f(u16 u) {
  union { unsigned int i; float f; } v; v.i = ((unsigned int)u) << 16; return v.f;
}
__device__ __forceinline__ u16 f2bf(float f) {
  union { float f; unsigned int i; } v; v.f = f;
  unsigned int x = v.i;
  return (u16)((x + 0x7fffu + ((x >> 16) & 1u)) >> 16);  // RNE
}

__device__ __forceinline__ void async16(const void* g, void* l) {
  __builtin_amdgcn_global_load_lds(
      (const __attribute__((address_space(1))) void*)g,
      (__attribute__((address_space(3))) void*)l, 16, 0, 0);
}

// ---------------------------------------------------------------- casts ----
__global__ __launch_bounds__(256) void cast_f32_to_bf16(
    const float* __restrict__ x, u16* __restrict__ y, long n) {
  long i = ((long)blockIdx.x * blockDim.x + threadIdx.x) * 8;
  long stride = (long)gridDim.x * blockDim.x * 8;
  for (long j = i; j < n; j += stride) {
    float4 a = ((const float4*)(x + j))[0];
    float4 b = ((const float4*)(x + j))[1];
    unsigned int p0 = (unsigned)f2bf(a.x) | ((unsigned)f2bf(a.y) << 16);
    unsigned int p1 = (unsigned)f2bf(a.z) | ((unsigned)f2bf(a.w) << 16);
    unsigned int p2 = (unsigned)f2bf(b.x) | ((unsigned)f2bf(b.y) << 16);
    unsigned int p3 = (unsigned)f2bf(b.z) | ((unsigned)f2bf(b.w) << 16);
    *(uint4*)(y + j) = make_uint4(p0, p1, p2, p3);
  }
}

// key fp32 -> Kb bf16 [b,n,c] AND KbT bf16 [b,c,n]
__global__ __launch_bounds__(256) void castKT(
    const float* __restrict__ Kin, u16* __restrict__ Kb, u16* __restrict__ KbT) {
  __shared__ u16 tile[32][34];
  int t = threadIdx.x;
  long b = blockIdx.z;
  int n0 = blockIdx.x * 32, c0 = blockIdx.y * 32;
  int nr = t >> 3, c4 = (t & 7) * 4;
  float4 v = *(const float4*)(Kin + (b * 2048 + n0 + nr) * 512 + c0 + c4);
  unsigned q0 = f2bf(v.x), q1 = f2bf(v.y), q2 = f2bf(v.z), q3 = f2bf(v.w);
  *(uint2*)(Kb + (b * 2048 + n0 + nr) * 512 + c0 + c4) =
      make_uint2(q0 | (q1 << 16), q2 | (q3 << 16));
  tile[nr][c4] = (u16)q0; tile[nr][c4 + 1] = (u16)q1;
  tile[nr][c4 + 2] = (u16)q2; tile[nr][c4 + 3] = (u16)q3;
  __syncthreads();
  int cr = t >> 3, n4 = (t & 7) * 4;
  unsigned r0 = tile[n4][cr], r1 = tile[n4 + 1][cr];
  unsigned r2 = tile[n4 + 2][cr], r3 = tile[n4 + 3][cr];
  *(uint2*)(KbT + (b * 512 + c0 + cr) * 2048 + n0 + n4) =
      make_uint2(r0 | (r1 << 16), r2 | (r3 << 16));
}

// ------------------------------------------------- small weight kernels ----
// GT[i,j] = sum_d Wk[i,d]*Wq[j,d]  (fp32 acc, bf16 out)  grid(32,32)x256
__global__ __launch_bounds__(256) void smallGT(
    const float* __restrict__ Ai, const float* __restrict__ Bi, u16* __restrict__ C) {
  __shared__ float As[16][65], Bs[16][65];
  int t = threadIdx.x;
  int i0 = blockIdx.y * 16, j0 = blockIdx.x * 16;
  int r = t >> 4, c4 = (t & 15) * 4;
  int ty = t >> 4, tx = t & 15;
  float acc = 0.f;
  for (int d0 = 0; d0 < 512; d0 += 64) {
    float4 a = *(const float4*)(Ai + (i0 + r) * 512 + d0 + c4);
    float4 b = *(const float4*)(Bi + (j0 + r) * 512 + d0 + c4);
    __syncthreads();
    As[r][c4] = a.x; As[r][c4 + 1] = a.y; As[r][c4 + 2] = a.z; As[r][c4 + 3] = a.w;
    Bs[r][c4] = b.x; Bs[r][c4 + 1] = b.y; Bs[r][c4 + 2] = b.z; Bs[r][c4 + 3] = b.w;
    __syncthreads();
#pragma unroll
    for (int d = 0; d < 64; ++d) acc += As[ty][d] * Bs[tx][d];
  }
  C[(i0 + ty) * 512 + j0 + tx] = f2bf(acc);
}

// W2T[n,k] = sum_d Wv[k,d]*Wo[d,n]  grid(32,32)x256 (x->k0, y->n0)
__global__ __launch_bounds__(256) void smallW2T(
    const float* __restrict__ Wv, const float* __restrict__ Wo, u16* __restrict__ C) {
  __shared__ float Vs[16][65];
  __shared__ float Os[64][17];
  int t = threadIdx.x;
  int k0 = blockIdx.x * 16, n0 = blockIdx.y * 16;
  int r = t >> 4, c4 = (t & 15) * 4;
  int dd = t >> 2, nn4 = (t & 3) * 4;
  int ty = t >> 4, tx = t & 15;
  float acc = 0.f;
  for (int d0 = 0; d0 < 512; d0 += 64) {
    float4 a = *(const float4*)(Wv + (k0 + r) * 512 + d0 + c4);
    float4 b = *(const float4*)(Wo + (long)(d0 + dd) * 512 + n0 + nn4);
    __syncthreads();
    Vs[r][c4] = a.x; Vs[r][c4 + 1] = a.y; Vs[r][c4 + 2] = a.z; Vs[r][c4 + 3] = a.w;
    Os[dd][nn4] = b.x; Os[dd][nn4 + 1] = b.y; Os[dd][nn4 + 2] = b.z; Os[dd][nn4 + 3] = b.w;
    __syncthreads();
#pragma unroll
    for (int d = 0; d < 64; ++d) acc += Vs[tx][d] * Os[d][ty];
  }
  C[(n0 + ty) * 512 + k0 + tx] = f2bf(acc);
}

// w[c] = (sum_d Wk[c,d]*bq[d]) / 512   grid(512)x256
__global__ __launch_bounds__(256) void wveck(
    const float* __restrict__ Wk, const float* __restrict__ bq, float* __restrict__ wv) {
  int c = blockIdx.x, t = threadIdx.x;
  float s = 0.f;
  for (int d = t; d < 512; d += 256) s += Wk[c * 512 + d] * bq[d];
  for (int off = 32; off; off >>= 1) s += __shfl_xor(s, off);
  __shared__ float r4[4];
  if ((t & 63) == 0) r4[t >> 6] = s;
  __syncthreads();
  if (t == 0) wv[c] = (r4[0] + r4[1] + r4[2] + r4[3]) * (1.0f / 512.0f);
}

// c2[e] = (sum_d bv[d]*Wo[d,e]) / 2048 + bo[e]   grid(2)x256
__global__ __launch_bounds__(256) void cveck(
    const float* __restrict__ Wo, const float* __restrict__ bv,
    const float* __restrict__ bo, float* __restrict__ c2) {
  int e = blockIdx.x * 256 + threadIdx.x;
  float s = 0.f;
  for (int d = 0; d < 512; ++d) s += bv[d] * Wo[d * 512 + e];
  c2[e] = s * (1.0f / 2048.0f) + bo[e];
}

// beta[row] = sum_c Kb[row,c]*w[c]   (w already has /512)  grid(16384)x256
__global__ __launch_bounds__(256) void betak(
    const u16* __restrict__ Kb, const float* __restrict__ wv, float* __restrict__ beta) {
  __shared__ float ws[512];
  int t = threadIdx.x, lane = t & 63, wid = t >> 6;
  ws[t] = wv[t];
  ws[t + 256] = wv[t + 256];
  __syncthreads();
  long row = (long)blockIdx.x * 4 + wid;
  bf16x8 v = *(const bf16x8*)(Kb + row * 512 + lane * 8);
  float s = 0.f;
#pragma unroll
  for (int j = 0; j < 8; ++j) s += bf2f((u16)v[j]) * ws[lane * 8 + j];
  for (int off = 32; off; off >>= 1) s += __shfl_xor(s, off);
  if (lane == 0) beta[row] = s;
}

// --------------------------------------------------- 256x128 4-wave gemm ----
// C[m,n] = scale*sum_k A[m,k]*B[n,k] (+bias[z*sBias+n]); BK=32, 2-buf LDS.
// acc[8][4] per wave (per-wave 128x64 output): 0.034 LDS-B/FLOP -> ~80% LDS
// ceiling; 48 KiB LDS + launch_bounds(256,3) -> 3 blocks/CU for cross-block
// overlap of the barrier drain (m114). Read swizzle byte^=((row>>1)&3)<<4
// (measured conflict-free); staging = linear LDS dest + inv-swizzled source.
template <int MODE>
__global__ __launch_bounds__(256, 3) void gemm(
    const u16* __restrict__ A, const u16* __restrict__ B,
    const float* __restrict__ bias, long sBias, void* __restrict__ Cout,
    int N, int K, long sA, long sB, long sC, float scale) {
  __shared__ __align__(16) char lds[2][24576];  // per buf: A 16K | B 8K
  const int t = threadIdx.x;
  const int lane = t & 63;
  const int w = t >> 6;        // 0..3
  const int wm = w >> 1;       // 0..1 (row half)
  const int wn = w & 1;        // 0..1 (col half)
  const long z = blockIdx.z;
  const long m0 = (long)blockIdx.x * 256;
  const int n0 = blockIdx.y * 128;
  const int nt = K >> 5;

  // staging: linear LDS dest, inverse-swizzled global source
  const int srow = w * 16 + (lane >> 2);                  // 0..63
  const int koff = 8 * ((lane & 3) ^ ((lane >> 3) & 3));  // elems
  const u16* pa = A + z * sA + (m0 + srow) * (long)K + koff;
  const u16* pb = B + z * sB + ((long)(n0 + srow)) * K + koff;
  const int ldsW = w * 1024;   // wave-uniform

  // reads: swizzled ds_read_b128
  const int fr = lane & 15;
  const int kb = (lane >> 4) * 16;
  const int sw = ((fr >> 1) & 3) << 4;
  const int aoff = (wm * 128 + fr) * 64 + (kb ^ sw);        // + mi*1024
  const int boff = 16384 + (wn * 64 + fr) * 64 + (kb ^ sw); // + ni*1024

  f32x4 acc[8][4] = {};

  // prologue: stage tile 0 -> buf 0
  {
    char* d = lds[0] + ldsW;
#pragma unroll
    for (int c = 0; c < 4; ++c) async16(pa + (long)c * 64 * K, d + c * 4096);
#pragma unroll
    for (int c = 0; c < 2; ++c) async16(pb + (long)c * 64 * K, d + 16384 + c * 4096);
    pa += 32; pb += 32;
  }
  __syncthreads();

  int cur = 0;
  for (int tt = 0; tt < nt; ++tt) {
    if (tt + 1 < nt) {
      char* d = lds[cur ^ 1] + ldsW;
#pragma unroll
      for (int c = 0; c < 4; ++c) async16(pa + (long)c * 64 * K, d + c * 4096);
#pragma unroll
      for (int c = 0; c < 2; ++c) async16(pb + (long)c * 64 * K, d + 16384 + c * 4096);
      pa += 32; pb += 32;
    }
    const char* rb = lds[cur];
    bf16x8 bf[4];
#pragma unroll
    for (int ni = 0; ni < 4; ++ni)
      bf[ni] = *(const bf16x8*)(rb + boff + ni * 1024);
    __builtin_amdgcn_s_setprio(1);
#pragma unroll
    for (int mi = 0; mi < 8; ++mi) {
      bf16x8 af = *(const bf16x8*)(rb + aoff + mi * 1024);
#pragma unroll
      for (int ni = 0; ni < 4; ++ni)
        acc[mi][ni] = __builtin_amdgcn_mfma_f32_16x16x32_bf16(af, bf[ni], acc[mi][ni], 0, 0, 0);
    }
    __builtin_amdgcn_s_setprio(0);
    __syncthreads();
    cur ^= 1;
  }

  // epilogue
  const int er = (lane >> 4) * 4;
  const int ec = lane & 15;
  if (MODE == 0) {
    // coalesced via LDS transpose: 2 passes x 128 rows, stride 136 u16
    u16* Ep = (u16*)lds;
    u16* Cp = (u16*)Cout + z * sC;
    float bvv[4];
#pragma unroll
    for (int ni = 0; ni < 4; ++ni)
      bvv[ni] = bias ? bias[z * sBias + n0 + wn * 64 + ni * 16 + ec] : 0.0f;
#pragma unroll
    for (int p = 0; p < 2; ++p) {
      __syncthreads();
      if (wm == p) {
#pragma unroll
        for (int mi = 0; mi < 8; ++mi)
#pragma unroll
          for (int ni = 0; ni < 4; ++ni)
#pragma unroll
            for (int i = 0; i < 4; ++i)
              Ep[(mi * 16 + er + i) * 136 + wn * 64 + ni * 16 + ec] =
                  f2bf(acc[mi][ni][i] * scale + bvv[ni]);
      }
      __syncthreads();
#pragma unroll
      for (int s = 0; s < 8; ++s) {
        int idx = s * 256 + t;
        int R = idx >> 4;   // 0..127
        int j = idx & 15;
        uint4 d = *(const uint4*)(Ep + R * 136 + j * 8);
        *(uint4*)(Cp + (m0 + p * 128 + R) * (long)N + n0 + j * 8) = d;
      }
    }
  } else {
    float* Cp = (float*)Cout + z * sC;
#pragma unroll
    for (int mi = 0; mi < 8; ++mi)
#pragma unroll
      for (int ni = 0; ni < 4; ++ni)
#pragma unroll
        for (int i = 0; i < 4; ++i) {
          long gm = m0 + wm * 128 + mi * 16 + er + i;
          int gc = n0 + wn * 64 + ni * 16 + ec;
          float val = acc[mi][ni][i] * scale;
          if (bias) val += bias[gc];
          Cp[gm * (long)N + gc] = val;
        }
  }
}

// ------------------------------------------------------------- softmax ----
__global__ __launch_bounds__(256) void softmax_rows(u16* __restrict__ S, float inv) {
  long row = blockIdx.x;
  u16* p = S + row * 2048;
  int t = threadIdx.x;
  int lane = t & 63, wv = t >> 6;

  uint4 raw = ((const uint4*)p)[t];
  unsigned int wd[4] = {raw.x, raw.y, raw.z, raw.w};
  float v[8];
#pragma unroll
  for (int j = 0; j < 4; ++j) {
    v[2 * j]     = bf2f((u16)(wd[j] & 0xffffu));
    v[2 * j + 1] = bf2f((u16)(wd[j] >> 16));
  }
  float mx = v[0];
#pragma unroll
  for (int j = 1; j < 8; ++j) mx = fmaxf(mx, v[j]);
  for (int off = 32; off; off >>= 1) mx = fmaxf(mx, __shfl_xor(mx, off));
  __shared__ float rmax[4], rsum[4];
  if (lane == 0) rmax[wv] = mx;
  __syncthreads();
  mx = fmaxf(fmaxf(rmax[0], rmax[1]), fmaxf(rmax[2], rmax[3]));

  float e[8], s = 0.f;
#pragma unroll
  for (int j = 0; j < 8; ++j) { e[j] = __expf(v[j] - mx); s += e[j]; }
  for (int off = 32; off; off >>= 1) s += __shfl_xor(s, off);
  if (lane == 0) rsum[wv] = s;
  __syncthreads();
  s = rsum[0] + rsum[1] + rsum[2] + rsum[3];

  float r = inv / s;
  unsigned int o[4];
#pragma unroll
  for (int j = 0; j < 4; ++j)
    o[j] = (unsigned)f2bf(e[2 * j] * r) | ((unsigned)f2bf(e[2 * j + 1] * r) << 16);
  ((uint4*)p)[t] = make_uint4(o[0], o[1], o[2], o[3]);
}

// -------------------------------------------------------------- launch ----
extern "C" void kernel_launch(void* const* d_in, const int* in_sizes, int n_in,
                              void* d_out, int out_size, void* d_ws, size_t ws_size,
                              hipStream_t stream) {
  const float* query = (const float*)d_in[0];
  const float* key_  = (const float*)d_in[1];
  const float* Wq = (const float*)d_in[2];
  const float* bq = (const float*)d_in[3];
  const float* Wk = (const float*)d_in[4];
  const float* bk = (const float*)d_in[5];  // row-constant in scores: cancels
  const float* Wv = (const float*)d_in[6];
  const float* bv = (const float*)d_in[7];
  const float* Wo = (const float*)d_in[8];
  const float* bo = (const float*)d_in[9];
  (void)bk;
  float* out = (float*)d_out;

  const long tokE = 65536L * 512;
  const long bstride = 2048L * 512;

  char* ws = (char*)d_ws;
  u16* Qb   = (u16*)(ws);                     // 64 MB (reused as attn)
  u16* Kb   = (u16*)(ws + 67108864L);         // 64 MB
  u16* KbT  = (u16*)(ws + 134217728L);        // 64 MB
  u16* GT   = (u16*)(ws + 201326592L);        // 0.5 MB
  u16* W2T  = (u16*)(ws + 201850880L);        // 0.5 MB
  float* wv   = (float*)(ws + 202375168L);    // 2 KB
  float* c2   = (float*)(ws + 202377216L);    // 2 KB
  float* beta = (float*)(ws + 202379264L);    // 256 KB
  char* Sbase = ws + 203423744L;
  u16* attn = Qb;                             // Qb dead after q'-proj

  u16* qb = (u16*)d_out;                      // 64 MB scratch in d_out

  long s_avail = (long)ws_size - 203423744L;
  int g = (int)(s_avail / 8388608L);
  if (g < 1) g = 1;
  if (g > 32) g = 32;

  // 1. casts + fused weights
  cast_f32_to_bf16<<<16384, 256, 0, stream>>>(query, Qb, tokE);
  castKT<<<dim3(64, 16, 32), 256, 0, stream>>>(key_, Kb, KbT);
  smallGT<<<dim3(32, 32), 256, 0, stream>>>(Wk, Wq, GT);    // GT[n,c]
  smallW2T<<<dim3(32, 32), 256, 0, stream>>>(Wv, Wo, W2T);  // W2T[e,k]
  wveck<<<512, 256, 0, stream>>>(Wk, bq, wv);
  cveck<<<2, 256, 0, stream>>>(Wo, bv, bo, c2);
  betak<<<16384, 256, 0, stream>>>(Kb, wv, beta);

  // 2. q' = Q @ (Wq Wk^T)   [65536 x 512]
  gemm<0><<<dim3(256, 4, 1), 256, 0, stream>>>(Qb, GT, nullptr, 0, qb,
                                               512, 512, 0, 0, 0, 1.0f);

  // 3. attention per group: S = q'.Kin^T/512 + beta; softmax; T = P.Kin/2048
  for (int b0 = 0; b0 < 32; b0 += g) {
    int bc = (32 - b0 < g) ? (32 - b0) : g;
    u16* Sg = (u16*)Sbase;
    gemm<0><<<dim3(8, 16, bc), 256, 0, stream>>>(
        qb + (long)b0 * bstride, Kb + (long)b0 * bstride,
        beta + (long)b0 * 2048, 2048, Sg, 2048, 512,
        bstride, bstride, 2048L * 2048, 1.0f / 512.0f);
    softmax_rows<<<bc * 2048, 256, 0, stream>>>(Sg, 1.0f / 2048.0f);
    gemm<0><<<dim3(8, 4, bc), 256, 0, stream>>>(
        Sg, KbT + (long)b0 * bstride, nullptr, 0,
        attn + (long)b0 * bstride, 512, 2048,
        2048L * 2048, bstride, bstride, 1.0f);
  }

  // 4. out = T @ (Wv Wo) + c2   (fp32)
  gemm<2><<<dim3(256, 4, 1), 256, 0, stream>>>(attn, W2T, c2, 0, out,
                                               512, 512, 0, 0, 0, 1.0f);
}

// Round 8
// 716.453 us; speedup vs baseline: 1.1964x; 1.0736x over previous
//
#include <hip/hip_runtime.h>
#include <stdint.h>

typedef unsigned short u16;
typedef __attribute__((ext_vector_type(8))) short bf16x8;
typedef __attribute__((ext_vector_type(4))) float f32x4;
typedef __attribute__((ext_vector_type(2))) unsigned int u32x2;
typedef __attribute__((ext_vector_type(4))) unsigned int u32x4;

__device__ __forceinline__ float bf2f(u16 u) {
  union { unsigned int i; float f; } v; v.i = ((unsigned int)u) << 16; return v.f;
}
__device__ __forceinline__ u16 f2bf(float f) {
  union { float f; unsigned int i; } v; v.f = f;
  unsigned int x = v.i;
  return (u16)((x + 0x7fffu + ((x >> 16) & 1u)) >> 16);  // RNE
}

__device__ __forceinline__ void async16(const void* g, void* l) {
  __builtin_amdgcn_global_load_lds(
      (const __attribute__((address_space(1))) void*)g,
      (__attribute__((address_space(3))) void*)l, 16, 0, 0);
}

// ---------------------------------------------------------------- casts ----
__global__ __launch_bounds__(256) void cast_f32_to_bf16(
    const float* __restrict__ x, u16* __restrict__ y, long n) {
  long i = ((long)blockIdx.x * blockDim.x + threadIdx.x) * 8;
  long stride = (long)gridDim.x * blockDim.x * 8;
  for (long j = i; j < n; j += stride) {
    float4 a = ((const float4*)(x + j))[0];
    float4 b = ((const float4*)(x + j))[1];
    u32x4 o;
    o.x = (unsigned)f2bf(a.x) | ((unsigned)f2bf(a.y) << 16);
    o.y = (unsigned)f2bf(a.z) | ((unsigned)f2bf(a.w) << 16);
    o.z = (unsigned)f2bf(b.x) | ((unsigned)f2bf(b.y) << 16);
    o.w = (unsigned)f2bf(b.z) | ((unsigned)f2bf(b.w) << 16);
    __builtin_nontemporal_store(o, (u32x4*)(y + j));
  }
}

// key fp32 -> Kb bf16 [b,n,c] AND KbT bf16 [b,c,n]
__global__ __launch_bounds__(256) void castKT(
    const float* __restrict__ Kin, u16* __restrict__ Kb, u16* __restrict__ KbT) {
  __shared__ u16 tile[32][34];
  int t = threadIdx.x;
  long b = blockIdx.z;
  int n0 = blockIdx.x * 32, c0 = blockIdx.y * 32;
  int nr = t >> 3, c4 = (t & 7) * 4;
  float4 v = *(const float4*)(Kin + (b * 2048 + n0 + nr) * 512 + c0 + c4);
  unsigned q0 = f2bf(v.x), q1 = f2bf(v.y), q2 = f2bf(v.z), q3 = f2bf(v.w);
  u32x2 o1; o1.x = q0 | (q1 << 16); o1.y = q2 | (q3 << 16);
  __builtin_nontemporal_store(o1, (u32x2*)(Kb + (b * 2048 + n0 + nr) * 512 + c0 + c4));
  tile[nr][c4] = (u16)q0; tile[nr][c4 + 1] = (u16)q1;
  tile[nr][c4 + 2] = (u16)q2; tile[nr][c4 + 3] = (u16)q3;
  __syncthreads();
  int cr = t >> 3, n4 = (t & 7) * 4;
  unsigned r0 = tile[n4][cr], r1 = tile[n4 + 1][cr];
  unsigned r2 = tile[n4 + 2][cr], r3 = tile[n4 + 3][cr];
  u32x2 o2; o2.x = r0 | (r1 << 16); o2.y = r2 | (r3 << 16);
  __builtin_nontemporal_store(o2, (u32x2*)(KbT + (b * 512 + c0 + cr) * 2048 + n0 + n4));
}

// ------------------------------------------------- small weight kernels ----
__global__ __launch_bounds__(256) void smallGT(
    const float* __restrict__ Ai, const float* __restrict__ Bi, u16* __restrict__ C) {
  __shared__ float As[16][65], Bs[16][65];
  int t = threadIdx.x;
  int i0 = blockIdx.y * 16, j0 = blockIdx.x * 16;
  int r = t >> 4, c4 = (t & 15) * 4;
  int ty = t >> 4, tx = t & 15;
  float acc = 0.f;
  for (int d0 = 0; d0 < 512; d0 += 64) {
    float4 a = *(const float4*)(Ai + (i0 + r) * 512 + d0 + c4);
    float4 b = *(const float4*)(Bi + (j0 + r) * 512 + d0 + c4);
    __syncthreads();
    As[r][c4] = a.x; As[r][c4 + 1] = a.y; As[r][c4 + 2] = a.z; As[r][c4 + 3] = a.w;
    Bs[r][c4] = b.x; Bs[r][c4 + 1] = b.y; Bs[r][c4 + 2] = b.z; Bs[r][c4 + 3] = b.w;
    __syncthreads();
#pragma unroll
    for (int d = 0; d < 64; ++d) acc += As[ty][d] * Bs[tx][d];
  }
  C[(i0 + ty) * 512 + j0 + tx] = f2bf(acc);
}

__global__ __launch_bounds__(256) void smallW2T(
    const float* __restrict__ Wv, const float* __restrict__ Wo, u16* __restrict__ C) {
  __shared__ float Vs[16][65];
  __shared__ float Os[64][17];
  int t = threadIdx.x;
  int k0 = blockIdx.x * 16, n0 = blockIdx.y * 16;
  int r = t >> 4, c4 = (t & 15) * 4;
  int dd = t >> 2, nn4 = (t & 3) * 4;
  int ty = t >> 4, tx = t & 15;
  float acc = 0.f;
  for (int d0 = 0; d0 < 512; d0 += 64) {
    float4 a = *(const float4*)(Wv + (k0 + r) * 512 + d0 + c4);
    float4 b = *(const float4*)(Wo + (long)(d0 + dd) * 512 + n0 + nn4);
    __syncthreads();
    Vs[r][c4] = a.x; Vs[r][c4 + 1] = a.y; Vs[r][c4 + 2] = a.z; Vs[r][c4 + 3] = a.w;
    Os[dd][nn4] = b.x; Os[dd][nn4 + 1] = b.y; Os[dd][nn4 + 2] = b.z; Os[dd][nn4 + 3] = b.w;
    __syncthreads();
#pragma unroll
    for (int d = 0; d < 64; ++d) acc += Vs[tx][d] * Os[d][ty];
  }
  C[(n0 + ty) * 512 + k0 + tx] = f2bf(acc);
}

__global__ __launch_bounds__(256) void wveck(
    const float* __restrict__ Wk, const float* __restrict__ bq, float* __restrict__ wv) {
  int c = blockIdx.x, t = threadIdx.x;
  float s = 0.f;
  for (int d = t; d < 512; d += 256) s += Wk[c * 512 + d] * bq[d];
  for (int off = 32; off; off >>= 1) s += __shfl_xor(s, off);
  __shared__ float r4[4];
  if ((t & 63) == 0) r4[t >> 6] = s;
  __syncthreads();
  if (t == 0) wv[c] = (r4[0] + r4[1] + r4[2] + r4[3]) * (1.0f / 512.0f);
}

__global__ __launch_bounds__(256) void cveck(
    const float* __restrict__ Wo, const float* __restrict__ bv,
    const float* __restrict__ bo, float* __restrict__ c2) {
  int e = blockIdx.x * 256 + threadIdx.x;
  float s = 0.f;
  for (int d = 0; d < 512; ++d) s += bv[d] * Wo[d * 512 + e];
  c2[e] = s * (1.0f / 2048.0f) + bo[e];
}

__global__ __launch_bounds__(256) void betak(
    const u16* __restrict__ Kb, const float* __restrict__ wv, float* __restrict__ beta) {
  __shared__ float ws[512];
  int t = threadIdx.x, lane = t & 63, wid = t >> 6;
  ws[t] = wv[t];
  ws[t + 256] = wv[t + 256];
  __syncthreads();
  long row = (long)blockIdx.x * 4 + wid;
  bf16x8 v = *(const bf16x8*)(Kb + row * 512 + lane * 8);
  float s = 0.f;
#pragma unroll
  for (int j = 0; j < 8; ++j) s += bf2f((u16)v[j]) * ws[lane * 8 + j];
  for (int off = 32; off; off >>= 1) s += __shfl_xor(s, off);
  if (lane == 0) beta[row] = s;
}

// --------------------------------------------------- 256x128 4-wave gemm ----
// C[m,n] = scale*sum_k A[m,k]*B[n,k] (+bias[z*sBias+n]); BK=32, 2-buf LDS.
// Flat 1-D grid with XCD-pinned decode (T1): when Z%8==0, batch z is pinned
// to XCD wg&7 so its A/B panels stay resident in that XCD's 4 MB L2.
// nfast=1 orders n fastest (reuse A-panel), else m fastest.
// Non-temporal C stores keep S/out streams from thrashing L2.
template <int MODE>
__global__ __launch_bounds__(256, 3) void gemm(
    const u16* __restrict__ A, const u16* __restrict__ B,
    const float* __restrict__ bias, long sBias, void* __restrict__ Cout,
    int N, int K, long sA, long sB, long sC, float scale,
    int mT, int nT, int Z, int nfast) {
  __shared__ __align__(16) char lds[2][24576];  // per buf: A 16K | B 8K
  const int t = threadIdx.x;
  const int lane = t & 63;
  const int w = t >> 6;        // 0..3
  const int wm = w >> 1;       // 0..1 (row half)
  const int wn = w & 1;        // 0..1 (col half)

  // ---- block decode ----
  const int wg = blockIdx.x;
  const int nb = mT * nT;
  long z; int within;
  if (Z > 1 && (Z & 7) == 0) {
    int xcd = wg & 7;
    int sub = wg >> 3;
    z = (long)(sub / nb) * 8 + xcd;
    within = sub % nb;
  } else {
    z = wg / nb;
    within = wg % nb;
  }
  int bx, by;
  if (nfast) { by = within % nT; bx = within / nT; }
  else       { bx = within % mT; by = within / mT; }
  const long m0 = (long)bx * 256;
  const int n0 = by * 128;
  const int nt = K >> 5;

  // staging: linear LDS dest, inverse-swizzled global source
  const int srow = w * 16 + (lane >> 2);                  // 0..63
  const int koff = 8 * ((lane & 3) ^ ((lane >> 3) & 3));  // elems
  const u16* pa = A + z * sA + (m0 + srow) * (long)K + koff;
  const u16* pb = B + z * sB + ((long)(n0 + srow)) * K + koff;
  const int ldsW = w * 1024;   // wave-uniform

  // reads: swizzled ds_read_b128
  const int fr = lane & 15;
  const int kb = (lane >> 4) * 16;
  const int sw = ((fr >> 1) & 3) << 4;
  const int aoff = (wm * 128 + fr) * 64 + (kb ^ sw);        // + mi*1024
  const int boff = 16384 + (wn * 64 + fr) * 64 + (kb ^ sw); // + ni*1024

  f32x4 acc[8][4] = {};

  // prologue: stage tile 0 -> buf 0
  {
    char* d = lds[0] + ldsW;
#pragma unroll
    for (int c = 0; c < 4; ++c) async16(pa + (long)c * 64 * K, d + c * 4096);
#pragma unroll
    for (int c = 0; c < 2; ++c) async16(pb + (long)c * 64 * K, d + 16384 + c * 4096);
    pa += 32; pb += 32;
  }
  __syncthreads();

  int cur = 0;
  for (int tt = 0; tt < nt; ++tt) {
    if (tt + 1 < nt) {
      char* d = lds[cur ^ 1] + ldsW;
#pragma unroll
      for (int c = 0; c < 4; ++c) async16(pa + (long)c * 64 * K, d + c * 4096);
#pragma unroll
      for (int c = 0; c < 2; ++c) async16(pb + (long)c * 64 * K, d + 16384 + c * 4096);
      pa += 32; pb += 32;
    }
    const char* rb = lds[cur];
    bf16x8 bf[4];
#pragma unroll
    for (int ni = 0; ni < 4; ++ni)
      bf[ni] = *(const bf16x8*)(rb + boff + ni * 1024);
    __builtin_amdgcn_s_setprio(1);
#pragma unroll
    for (int mi = 0; mi < 8; ++mi) {
      bf16x8 af = *(const bf16x8*)(rb + aoff + mi * 1024);
#pragma unroll
      for (int ni = 0; ni < 4; ++ni)
        acc[mi][ni] = __builtin_amdgcn_mfma_f32_16x16x32_bf16(af, bf[ni], acc[mi][ni], 0, 0, 0);
    }
    __builtin_amdgcn_s_setprio(0);
    __syncthreads();
    cur ^= 1;
  }

  // epilogue
  const int er = (lane >> 4) * 4;
  const int ec = lane & 15;
  float bvv[4];
#pragma unroll
  for (int ni = 0; ni < 4; ++ni)
    bvv[ni] = bias ? bias[z * sBias + n0 + wn * 64 + ni * 16 + ec] : 0.0f;
  if (MODE == 0) {
    // bf16 coalesced via LDS transpose: 2 passes x 128 rows, stride 136 u16
    u16* Ep = (u16*)lds;
    u16* Cp = (u16*)Cout + z * sC;
#pragma unroll
    for (int p = 0; p < 2; ++p) {
      __syncthreads();
      if (wm == p) {
#pragma unroll
        for (int mi = 0; mi < 8; ++mi)
#pragma unroll
          for (int ni = 0; ni < 4; ++ni)
#pragma unroll
            for (int i = 0; i < 4; ++i)
              Ep[(mi * 16 + er + i) * 136 + wn * 64 + ni * 16 + ec] =
                  f2bf(acc[mi][ni][i] * scale + bvv[ni]);
      }
      __syncthreads();
#pragma unroll
      for (int s = 0; s < 8; ++s) {
        int idx = s * 256 + t;
        int R = idx >> 4;   // 0..127
        int j = idx & 15;
        u32x4 d = *(const u32x4*)(Ep + R * 136 + j * 8);
        __builtin_nontemporal_store(
            d, (u32x4*)(Cp + (m0 + p * 128 + R) * (long)N + n0 + j * 8));
      }
    }
  } else {
    // fp32 coalesced via LDS transpose: 4 passes x 64 rows, stride 132 f32
    float* Ep = (float*)lds;
    float* Cp = (float*)Cout + z * sC;
#pragma unroll
    for (int p = 0; p < 4; ++p) {
      __syncthreads();
      if (wm == (p >> 1)) {
#pragma unroll
        for (int mi2 = 0; mi2 < 4; ++mi2) {
          int mi = (p & 1) * 4 + mi2;
#pragma unroll
          for (int ni = 0; ni < 4; ++ni)
#pragma unroll
            for (int i = 0; i < 4; ++i)
              Ep[(mi2 * 16 + er + i) * 132 + wn * 64 + ni * 16 + ec] =
                  acc[mi][ni][i] * scale + bvv[ni];
        }
      }
      __syncthreads();
#pragma unroll
      for (int s = 0; s < 8; ++s) {
        int idx = s * 256 + t;
        int R = idx >> 5;   // 0..63
        int j = idx & 31;   // 0..31
        f32x4 d = *(const f32x4*)(Ep + R * 132 + j * 4);
        __builtin_nontemporal_store(
            d, (f32x4*)(Cp + (m0 + p * 64 + R) * (long)N + n0 + j * 4));
      }
    }
  }
}

// ------------------------------------------------------------- softmax ----
// 4 rows/block, one wave per row, full row (2048) in registers.
__global__ __launch_bounds__(256) void softmax_rows(u16* __restrict__ S, float inv) {
  int t = threadIdx.x;
  int lane = t & 63, wv = t >> 6;
  long row = (long)blockIdx.x * 4 + wv;
  u16* p = S + row * 2048;
  uint4 raw[4];
#pragma unroll
  for (int q = 0; q < 4; ++q) raw[q] = ((const uint4*)p)[lane + 64 * q];
  float v[32];
#pragma unroll
  for (int q = 0; q < 4; ++q) {
    unsigned wd[4] = {raw[q].x, raw[q].y, raw[q].z, raw[q].w};
#pragma unroll
    for (int j = 0; j < 4; ++j) {
      v[q * 8 + 2 * j]     = bf2f((u16)(wd[j] & 0xffffu));
      v[q * 8 + 2 * j + 1] = bf2f((u16)(wd[j] >> 16));
    }
  }
  float mx = v[0];
#pragma unroll
  for (int j = 1; j < 32; ++j) mx = fmaxf(mx, v[j]);
  for (int off = 32; off; off >>= 1) mx = fmaxf(mx, __shfl_xor(mx, off));
  float s = 0.f;
#pragma unroll
  for (int j = 0; j < 32; ++j) { v[j] = __expf(v[j] - mx); s += v[j]; }
  for (int off = 32; off; off >>= 1) s += __shfl_xor(s, off);
  float r = inv / s;
#pragma unroll
  for (int q = 0; q < 4; ++q) {
    unsigned o[4];
#pragma unroll
    for (int j = 0; j < 4; ++j)
      o[j] = (unsigned)f2bf(v[q * 8 + 2 * j] * r) |
             ((unsigned)f2bf(v[q * 8 + 2 * j + 1] * r) << 16);
    ((uint4*)p)[lane + 64 * q] = make_uint4(o[0], o[1], o[2], o[3]);
  }
}

// -------------------------------------------------------------- launch ----
extern "C" void kernel_launch(void* const* d_in, const int* in_sizes, int n_in,
                              void* d_out, int out_size, void* d_ws, size_t ws_size,
                              hipStream_t stream) {
  const float* query = (const float*)d_in[0];
  const float* key_  = (const float*)d_in[1];
  const float* Wq = (const float*)d_in[2];
  const float* bq = (const float*)d_in[3];
  const float* Wk = (const float*)d_in[4];
  const float* bk = (const float*)d_in[5];  // row-constant in scores: cancels
  const float* Wv = (const float*)d_in[6];
  const float* bv = (const float*)d_in[7];
  const float* Wo = (const float*)d_in[8];
  const float* bo = (const float*)d_in[9];
  (void)bk;
  float* out = (float*)d_out;

  const long tokE = 65536L * 512;
  const long bstride = 2048L * 512;

  char* ws = (char*)d_ws;
  u16* Qb   = (u16*)(ws);                     // 64 MB (reused as attn)
  u16* Kb   = (u16*)(ws + 67108864L);         // 64 MB
  u16* KbT  = (u16*)(ws + 134217728L);        // 64 MB
  u16* GT   = (u16*)(ws + 201326592L);        // 0.5 MB
  u16* W2T  = (u16*)(ws + 201850880L);        // 0.5 MB
  float* wv   = (float*)(ws + 202375168L);    // 2 KB
  float* c2   = (float*)(ws + 202377216L);    // 2 KB
  float* beta = (float*)(ws + 202379264L);    // 256 KB
  char* Sbase = ws + 203423744L;
  u16* attn = Qb;                             // Qb dead after q'-proj

  u16* qb = (u16*)d_out;                      // 64 MB scratch in d_out

  long s_avail = (long)ws_size - 203423744L;
  int g = (int)(s_avail / 8388608L);
  if (g < 1) g = 1;
  if (g > 32) g = 32;
  if (g >= 8) g &= ~7;  // keep batches-per-dispatch a multiple of 8 (XCD pin)

  // 1. casts + fused weights
  cast_f32_to_bf16<<<16384, 256, 0, stream>>>(query, Qb, tokE);
  castKT<<<dim3(64, 16, 32), 256, 0, stream>>>(key_, Kb, KbT);
  smallGT<<<dim3(32, 32), 256, 0, stream>>>(Wk, Wq, GT);    // GT[n,c]
  smallW2T<<<dim3(32, 32), 256, 0, stream>>>(Wv, Wo, W2T);  // W2T[e,k]
  wveck<<<512, 256, 0, stream>>>(Wk, bq, wv);
  cveck<<<2, 256, 0, stream>>>(Wo, bv, bo, c2);
  betak<<<16384, 256, 0, stream>>>(Kb, wv, beta);

  // 2. q' = Q @ (Wq Wk^T)   [65536 x 512]
  gemm<0><<<256 * 4, 256, 0, stream>>>(Qb, GT, nullptr, 0, qb,
                                       512, 512, 0, 0, 0, 1.0f, 256, 4, 1, 0);

  // 3. attention per group: S = q'.Kin^T/512 + beta; softmax; T = P.Kin/2048
  for (int b0 = 0; b0 < 32; b0 += g) {
    int bc = (32 - b0 < g) ? (32 - b0) : g;
    u16* Sg = (u16*)Sbase;
    gemm<0><<<8 * 16 * bc, 256, 0, stream>>>(
        qb + (long)b0 * bstride, Kb + (long)b0 * bstride,
        beta + (long)b0 * 2048, 2048, Sg, 2048, 512,
        bstride, bstride, 2048L * 2048, 1.0f / 512.0f, 8, 16, bc, 0);
    softmax_rows<<<bc * 512, 256, 0, stream>>>(Sg, 1.0f / 2048.0f);
    gemm<0><<<8 * 4 * bc, 256, 0, stream>>>(
        Sg, KbT + (long)b0 * bstride, nullptr, 0,
        attn + (long)b0 * bstride, 512, 2048,
        2048L * 2048, bstride, bstride, 1.0f, 8, 4, bc, 1);
  }

  // 4. out = T @ (Wv Wo) + c2   (fp32)
  gemm<2><<<256 * 4, 256, 0, stream>>>(attn, W2T, c2, 0, out,
                                       512, 512, 0, 0, 0, 1.0f, 256, 4, 1, 0);
}